// Round 12
// baseline (13.985 us; speedup 1.0000x reference)
//
#include <hip/hip_runtime.h>

#define BATCH   512
#define NPRED   1176
#define NTGT    64
#define PRED_C  9
#define THREADS 512
#define NWAVE   8
#define WCHUNK  147                    // NPRED / NWAVE (exact)
#define SEGCAP  148                    // per-wave compaction capacity
#define NMASKW  ((NPRED + 31) / 32)    // 37
#define NRAW    (NPRED * PRED_C)       // 10584 floats = 2646 float4
#define NRAW4   (NRAW / 4)             // 2646 exactly
#define INVALID 0xFFFF

// fast transcendentals: map to v_exp_f32 / v_log_f32 sequences
__device__ __forceinline__ float fexp(float x)  { return __expf(x); }
__device__ __forceinline__ float flog(float x)  { return __logf(x); }

__global__ __launch_bounds__(THREADS) void det_loss_main(
    const float* __restrict__ pred,   // (B, N, 9)
    const float* __restrict__ tbox,   // (B, T, 4)
    const int*   __restrict__ tcls,   // (B, T)
    float* __restrict__ partial)      // (B,)
{
    __shared__ float  sraw[NRAW + 8];              // staged raw pred (linear)
    __shared__ float4 cbox[NWAVE * SEGCAP];        // kept boxes, per-wave segments
    __shared__ float  carea[NWAVE * SEGCAP];
    __shared__ unsigned short cidx[NWAVE * SEGCAP];
    __shared__ float4 stgt[NTGT];
    __shared__ unsigned int smask[NMASKW];
    __shared__ float  sbint[THREADS];
    __shared__ float  sbuni[THREADS];
    __shared__ unsigned short sbslot[THREADS];
    __shared__ float  shull[4];
    __shared__ float  sred[NWAVE];

    const int b   = blockIdx.x;
    const int tid = threadIdx.x;
    const int wv  = tid >> 6, ln = tid & 63;
    const float* pb = pred + (size_t)b * NRAW;

    if (tid < NMASKW) smask[tid] = 0u;

    // ---- stage the whole 42 KB pred slice, fully coalesced float4 ----
    {
        const float4* src4 = reinterpret_cast<const float4*>(pb);
        float4* dst4 = reinterpret_cast<float4*>(sraw);
        #pragma unroll
        for (int k = 0; k < 6; ++k) {              // 5*512 + 86 = 2646
            int idx = k * THREADS + tid;
            if (idx < NRAW4) dst4[idx] = src4[idx];
        }
    }

    // ---- targets + hull (wave 0, concurrent with staging) ----
    if (tid < NTGT) {
        float4 tb = *reinterpret_cast<const float4*>(
            tbox + ((size_t)b * NTGT + tid) * 4);
        stgt[tid] = tb;
        float x1 = tb.x, y1 = tb.y, x2 = tb.z, y2 = tb.w;
        for (int off = 32; off > 0; off >>= 1) {
            x1 = fminf(x1, __shfl_xor(x1, off));
            y1 = fminf(y1, __shfl_xor(y1, off));
            x2 = fmaxf(x2, __shfl_xor(x2, off));
            y2 = fmaxf(y2, __shfl_xor(y2, off));
        }
        if (tid == 0) {
            shull[0] = x1; shull[1] = y1; shull[2] = x2; shull[3] = y2;
        }
    }
    __syncthreads();

    const float hx1 = shull[0], hy1 = shull[1];
    const float hx2 = shull[2], hy2 = shull[3];

    // ---- decode (from LDS) + conf-BCE + hull-cull + wave-local compaction ----
    // wave wv owns contiguous n in [wv*147, (wv+1)*147): ascending-n within
    // wave and ascending-wave across waves => first-max tie-break preserved.
    float s_conf = 0.f;
    int wcount = 0;
    const int n0 = wv * WCHUNK;
    for (int i = 0; i < 3; ++i) {                  // ceil(147/64) == 3
        int r = i * 64 + ln;
        int n = n0 + r;
        bool keep = false;
        float4 bb; float area = 0.f;
        if (r < WCHUNK) {
            const float* p = sraw + n * PRED_C;    // banks 9n+c: 2-way, free
            float p0 = p[0], p1 = p[1], p2 = p[2], p3 = p[3], p4 = p[4];
            float cx = (p0 * 2.f - 1.f) * 736.f;   // IMG_W/2
            float cy = (p1 * 2.f - 1.f) * 416.f;   // IMG_H/2
            float w  = fexp(p2) * 32.f;            // 1472/46 == 32 exactly
            float h  = fexp(p3) * 32.f;            // 832/26  == 32 exactly
            bb = make_float4(cx - 0.5f * w, cy - 0.5f * h,
                             cx + 0.5f * w, cy + 0.5f * h);
            area = w * h;
            // logaddexp(0,x) = max(x,0) + log(1 + exp(-|x|))
            s_conf += fmaxf(p4, 0.f) + flog(1.f + fexp(-fabsf(p4)));
            keep = (bb.x < hx2) & (bb.z > hx1) & (bb.y < hy2) & (bb.w > hy1);
        }
        unsigned long long m = __ballot(keep);
        if (keep) {
            int pos  = wcount + __popcll(m & ((1ull << ln) - 1ull));
            int slot = wv * SEGCAP + pos;
            cbox[slot]  = bb;
            carea[slot] = area;
            cidx[slot]  = (unsigned short)n;
        }
        wcount += __popcll(m);                     // wave-uniform
    }
    __syncthreads();

    // ---- Phase B: per-target partial argmax over this wave's segment ----
    {
        float4 tb = stgt[ln];
        float a2 = (tb.z - tb.x) * (tb.w - tb.y);
        float binter = 0.f, buni = 1.f;
        int   bslot = INVALID;
        const int base = wv * SEGCAP;
        for (int j = 0; j < wcount; ++j) {
            float4 bb = cbox[base + j];            // LDS broadcast
            float a1  = carea[base + j];
            float ix1 = fmaxf(bb.x, tb.x);
            float iy1 = fmaxf(bb.y, tb.y);
            float ix2 = fminf(bb.z, tb.z);
            float iy2 = fminf(bb.w, tb.w);
            float iw  = fmaxf(ix2 - ix1, 0.f);
            float ih  = fmaxf(iy2 - iy1, 0.f);
            float inter = iw * ih;
            float uni   = (a1 + a2) - inter;
            bool better = inter * buni > binter * uni;  // strict: first wins
            binter = better ? inter : binter;
            buni   = better ? uni   : buni;
            bslot  = better ? (base + j) : bslot;
        }
        sbint[tid] = binter; sbuni[tid] = buni;
        sbslot[tid] = (unsigned short)bslot;
    }
    __syncthreads();

    // ---- Phase C (lanes 0..63): combine waves, box + cls loss, mask ----
    float s_box = 0.f, s_cls = 0.f;
    if (tid < NTGT) {
        float binter = sbint[tid], buni = sbuni[tid];
        int   bslot = sbslot[tid];
        for (int w = 1; w < NWAVE; ++w) {          // ascending: first-max wins
            float ci = sbint[w * 64 + tid];
            float cu = sbuni[w * 64 + tid];
            bool better = ci * buni > binter * cu;
            binter = better ? ci : binter;
            buni   = better ? cu : buni;
            bslot  = better ? sbslot[w * 64 + tid] : bslot;
        }
        int m; float4 pbx;
        if (bslot == INVALID) {                    // all IoU == 0 -> argmax = 0
            m = 0;
            float p0 = sraw[0], p1 = sraw[1], p2 = sraw[2], p3 = sraw[3];
            float cx = (p0 * 2.f - 1.f) * 736.f;
            float cy = (p1 * 2.f - 1.f) * 416.f;
            float w  = fexp(p2) * 32.f;
            float h  = fexp(p3) * 32.f;
            pbx = make_float4(cx - 0.5f * w, cy - 0.5f * h,
                              cx + 0.5f * w, cy + 0.5f * h);
        } else {
            m = cidx[bslot];
            pbx = cbox[bslot];
        }
        atomicOr(&smask[m >> 5], 1u << (m & 31));  // set semantics, deterministic

        float4 tb = stgt[tid];
        float d;
        d = fabsf(pbx.x - tb.x); s_box += (d < 1.f) ? 0.5f * d * d : d - 0.5f;
        d = fabsf(pbx.y - tb.y); s_box += (d < 1.f) ? 0.5f * d * d : d - 0.5f;
        d = fabsf(pbx.z - tb.z); s_box += (d < 1.f) ? 0.5f * d * d : d - 0.5f;
        d = fabsf(pbx.w - tb.w); s_box += (d < 1.f) ? 0.5f * d * d : d - 0.5f;

        const float* pc = sraw + m * PRED_C + 5;   // cls logits from LDS
        float x0 = pc[0], x1 = pc[1], x2 = pc[2], x3 = pc[3];
        float mx = fmaxf(fmaxf(x0, x1), fmaxf(x2, x3));
        float se = fexp(x0 - mx) + fexp(x1 - mx) + fexp(x2 - mx) + fexp(x3 - mx);
        float lse = mx + flog(se);
        int tc = tcls[(size_t)b * NTGT + tid];
        float xt = (tc == 0) ? x0 : (tc == 1) ? x1 : (tc == 2) ? x2 : x3;
        s_cls += lse - xt;
    }
    __syncthreads();

    // ---- Phase D: subtract matched conf logits (deduped via bitmask) ----
    float s_pos = 0.f;
    for (int n = tid; n < NPRED; n += THREADS)
        if (smask[n >> 5] & (1u << (n & 31))) s_pos += sraw[n * PRED_C + 4];

    // ---- block reduction of conf - pos + 5*box + cls ----
    float v = s_conf - s_pos + 5.f * s_box + s_cls;
    for (int off = 32; off > 0; off >>= 1)
        v += __shfl_down(v, off);
    if (ln == 0) sred[wv] = v;
    __syncthreads();
    if (tid == 0) {
        float t = 0.f;
        for (int i = 0; i < NWAVE; ++i) t += sred[i];
        partial[b] = t;
    }
}

__global__ __launch_bounds__(BATCH) void det_loss_final(
    const float* __restrict__ partial, float* __restrict__ out)
{
    int tid = threadIdx.x;
    float v = partial[tid];
    for (int off = 32; off > 0; off >>= 1)
        v += __shfl_down(v, off);
    __shared__ float s[8];
    if ((tid & 63) == 0) s[tid >> 6] = v;
    __syncthreads();
    if (tid == 0) {
        float t = 0.f;
        for (int i = 0; i < 8; ++i) t += s[i];
        *out = t * (1.f / BATCH);
    }
}

extern "C" void kernel_launch(void* const* d_in, const int* in_sizes, int n_in,
                              void* d_out, int out_size, void* d_ws, size_t ws_size,
                              hipStream_t stream) {
    const float* pred = (const float*)d_in[0];
    const float* tbox = (const float*)d_in[1];
    const int*   tcls = (const int*)d_in[2];
    float* out     = (float*)d_out;
    float* partial = (float*)d_ws;   // 512 floats, overwritten every call

    det_loss_main<<<BATCH, THREADS, 0, stream>>>(pred, tbox, tcls, partial);
    det_loss_final<<<1, BATCH, 0, stream>>>(partial, out);
}

// Round 13
// 13.249 us; speedup vs baseline: 1.0556x; 1.0556x over previous
//
#include <hip/hip_runtime.h>

#define BATCH   512
#define NPRED   1176
#define NTGT    64
#define PRED_C  9
#define THREADS 512
#define NWAVE   8
#define WCHUNK  147                    // NPRED / NWAVE (exact)
#define SEGCAP  148                    // per-wave compaction capacity
#define NMASKW  ((NPRED + 31) / 32)    // 37
#define INVALID 0xFFFF

// fast transcendentals: map to v_exp_f32 / v_log_f32 sequences
__device__ __forceinline__ float fexp(float x)  { return __expf(x); }
__device__ __forceinline__ float flog(float x)  { return __logf(x); }

__global__ __launch_bounds__(THREADS) void det_loss_main(
    const float* __restrict__ pred,   // (B, N, 9)
    const float* __restrict__ tbox,   // (B, T, 4)
    const int*   __restrict__ tcls,   // (B, T)
    float* __restrict__ partial)      // (B,)
{
    __shared__ float4 cbox[NWAVE * SEGCAP];        // kept boxes, per-wave segments
    __shared__ float  carea[NWAVE * SEGCAP];
    __shared__ unsigned short cidx[NWAVE * SEGCAP];
    __shared__ float4 stgt[NTGT];
    __shared__ float  slogit[NPRED];
    __shared__ unsigned int smask[NMASKW];
    __shared__ float  sbint[THREADS];
    __shared__ float  sbuni[THREADS];
    __shared__ unsigned short sbslot[THREADS];
    __shared__ float  shull[4];
    __shared__ float  sred[NWAVE];

    const int b   = blockIdx.x;
    const int tid = threadIdx.x;
    const int wv  = tid >> 6, ln = tid & 63;
    const float* pb = pred + (size_t)b * NPRED * PRED_C;

    if (tid < NMASKW) smask[tid] = 0u;

    // ---- prefetch this thread's 3 records (15 dwords) as one parallel batch ----
    float rp[3][5];
    const int n0 = wv * WCHUNK;
    #pragma unroll
    for (int i = 0; i < 3; ++i) {                  // ceil(147/64) == 3
        int r = i * 64 + ln;
        if (r < WCHUNK) {
            const float* p = pb + (n0 + r) * PRED_C;
            rp[i][0] = p[0]; rp[i][1] = p[1]; rp[i][2] = p[2];
            rp[i][3] = p[3]; rp[i][4] = p[4];
        }
    }

    // ---- targets + hull (wave 0 only) ----
    if (tid < NTGT) {
        float4 tb = *reinterpret_cast<const float4*>(
            tbox + ((size_t)b * NTGT + tid) * 4);
        stgt[tid] = tb;
        float x1 = tb.x, y1 = tb.y, x2 = tb.z, y2 = tb.w;
        for (int off = 32; off > 0; off >>= 1) {
            x1 = fminf(x1, __shfl_xor(x1, off));
            y1 = fminf(y1, __shfl_xor(y1, off));
            x2 = fmaxf(x2, __shfl_xor(x2, off));
            y2 = fmaxf(y2, __shfl_xor(y2, off));
        }
        if (tid == 0) {
            shull[0] = x1; shull[1] = y1; shull[2] = x2; shull[3] = y2;
        }
    }
    __syncthreads();

    const float hx1 = shull[0], hy1 = shull[1];
    const float hx2 = shull[2], hy2 = shull[3];

    // ---- fused decode + conf-BCE + hull-cull + wave-local compaction ----
    // wave wv owns contiguous n in [wv*147, (wv+1)*147): ascending-n within
    // wave and ascending-wave across waves => first-max tie-break preserved.
    float s_conf = 0.f;
    int wcount = 0;
    #pragma unroll
    for (int i = 0; i < 3; ++i) {
        int r = i * 64 + ln;
        int n = n0 + r;
        bool keep = false;
        float4 bb; float area = 0.f;
        if (r < WCHUNK) {
            float p0 = rp[i][0], p1 = rp[i][1], p2 = rp[i][2];
            float p3 = rp[i][3], p4 = rp[i][4];
            float cx = (p0 * 2.f - 1.f) * 736.f;   // IMG_W/2
            float cy = (p1 * 2.f - 1.f) * 416.f;   // IMG_H/2
            float w  = fexp(p2) * 32.f;            // 1472/46 == 32 exactly
            float h  = fexp(p3) * 32.f;            // 832/26  == 32 exactly
            bb = make_float4(cx - 0.5f * w, cy - 0.5f * h,
                             cx + 0.5f * w, cy + 0.5f * h);
            area = w * h;
            slogit[n] = p4;
            // logaddexp(0,x) = max(x,0) + log(1 + exp(-|x|))
            s_conf += fmaxf(p4, 0.f) + flog(1.f + fexp(-fabsf(p4)));
            keep = (bb.x < hx2) & (bb.z > hx1) & (bb.y < hy2) & (bb.w > hy1);
        }
        unsigned long long m = __ballot(keep);
        if (keep) {
            int pos  = wcount + __popcll(m & ((1ull << ln) - 1ull));
            int slot = wv * SEGCAP + pos;
            cbox[slot]  = bb;
            carea[slot] = area;
            cidx[slot]  = (unsigned short)n;
        }
        wcount += __popcll(m);                     // wave-uniform
    }
    __syncthreads();

    // ---- Phase B: per-target partial argmax over this wave's segment ----
    {
        float4 tb = stgt[ln];
        float a2 = (tb.z - tb.x) * (tb.w - tb.y);
        float binter = 0.f, buni = 1.f;
        int   bslot = INVALID;
        const int base = wv * SEGCAP;
        for (int j = 0; j < wcount; ++j) {
            float4 bb = cbox[base + j];            // LDS broadcast
            float a1  = carea[base + j];
            float ix1 = fmaxf(bb.x, tb.x);
            float iy1 = fmaxf(bb.y, tb.y);
            float ix2 = fminf(bb.z, tb.z);
            float iy2 = fminf(bb.w, tb.w);
            float iw  = fmaxf(ix2 - ix1, 0.f);
            float ih  = fmaxf(iy2 - iy1, 0.f);
            float inter = iw * ih;
            float uni   = (a1 + a2) - inter;
            bool better = inter * buni > binter * uni;  // strict: first wins
            binter = better ? inter : binter;
            buni   = better ? uni   : buni;
            bslot  = better ? (base + j) : bslot;
        }
        sbint[tid] = binter; sbuni[tid] = buni;
        sbslot[tid] = (unsigned short)bslot;
    }
    __syncthreads();

    // ---- Phase C (lanes 0..63): combine waves, box + cls loss, mask ----
    float s_box = 0.f, s_cls = 0.f;
    if (tid < NTGT) {
        float binter = sbint[tid], buni = sbuni[tid];
        int   bslot = sbslot[tid];
        for (int w = 1; w < NWAVE; ++w) {          // ascending: first-max wins
            float ci = sbint[w * 64 + tid];
            float cu = sbuni[w * 64 + tid];
            bool better = ci * buni > binter * cu;
            binter = better ? ci : binter;
            buni   = better ? cu : buni;
            bslot  = better ? sbslot[w * 64 + tid] : bslot;
        }
        int m; float4 pbx;
        if (bslot == INVALID) {                    // all IoU == 0 -> argmax = 0
            m = 0;
            float p0 = pb[0], p1 = pb[1], p2 = pb[2], p3 = pb[3];
            float cx = (p0 * 2.f - 1.f) * 736.f;
            float cy = (p1 * 2.f - 1.f) * 416.f;
            float w  = fexp(p2) * 32.f;
            float h  = fexp(p3) * 32.f;
            pbx = make_float4(cx - 0.5f * w, cy - 0.5f * h,
                              cx + 0.5f * w, cy + 0.5f * h);
        } else {
            m = cidx[bslot];
            pbx = cbox[bslot];
        }
        atomicOr(&smask[m >> 5], 1u << (m & 31));  // set semantics, deterministic

        float4 tb = stgt[tid];
        float d;
        d = fabsf(pbx.x - tb.x); s_box += (d < 1.f) ? 0.5f * d * d : d - 0.5f;
        d = fabsf(pbx.y - tb.y); s_box += (d < 1.f) ? 0.5f * d * d : d - 0.5f;
        d = fabsf(pbx.z - tb.z); s_box += (d < 1.f) ? 0.5f * d * d : d - 0.5f;
        d = fabsf(pbx.w - tb.w); s_box += (d < 1.f) ? 0.5f * d * d : d - 0.5f;

        const float* pc = pb + m * PRED_C + 5;
        float x0 = pc[0], x1 = pc[1], x2 = pc[2], x3 = pc[3];
        float mx = fmaxf(fmaxf(x0, x1), fmaxf(x2, x3));
        float se = fexp(x0 - mx) + fexp(x1 - mx) + fexp(x2 - mx) + fexp(x3 - mx);
        float lse = mx + flog(se);
        int tc = tcls[(size_t)b * NTGT + tid];
        float xt = (tc == 0) ? x0 : (tc == 1) ? x1 : (tc == 2) ? x2 : x3;
        s_cls += lse - xt;
    }
    __syncthreads();

    // ---- Phase D: subtract matched conf logits (deduped via bitmask) ----
    float s_pos = 0.f;
    for (int n = tid; n < NPRED; n += THREADS)
        if (smask[n >> 5] & (1u << (n & 31))) s_pos += slogit[n];

    // ---- block reduction of conf - pos + 5*box + cls ----
    float v = s_conf - s_pos + 5.f * s_box + s_cls;
    for (int off = 32; off > 0; off >>= 1)
        v += __shfl_down(v, off);
    if (ln == 0) sred[wv] = v;
    __syncthreads();
    if (tid == 0) {
        float t = 0.f;
        for (int i = 0; i < NWAVE; ++i) t += sred[i];
        partial[b] = t;
    }
}

__global__ __launch_bounds__(BATCH) void det_loss_final(
    const float* __restrict__ partial, float* __restrict__ out)
{
    int tid = threadIdx.x;
    float v = partial[tid];
    for (int off = 32; off > 0; off >>= 1)
        v += __shfl_down(v, off);
    __shared__ float s[8];
    if ((tid & 63) == 0) s[tid >> 6] = v;
    __syncthreads();
    if (tid == 0) {
        float t = 0.f;
        for (int i = 0; i < 8; ++i) t += s[i];
        *out = t * (1.f / BATCH);
    }
}

extern "C" void kernel_launch(void* const* d_in, const int* in_sizes, int n_in,
                              void* d_out, int out_size, void* d_ws, size_t ws_size,
                              hipStream_t stream) {
    const float* pred = (const float*)d_in[0];
    const float* tbox = (const float*)d_in[1];
    const int*   tcls = (const int*)d_in[2];
    float* out     = (float*)d_out;
    float* partial = (float*)d_ws;   // 512 floats, overwritten every call

    det_loss_main<<<BATCH, THREADS, 0, stream>>>(pred, tbox, tcls, partial);
    det_loss_final<<<1, BATCH, 0, stream>>>(partial, out);
}